// Round 1
// baseline (278.446 us; speedup 1.0000x reference)
//
#include <hip/hip_runtime.h>

typedef __bf16 bf16;
typedef bf16 bf16x8 __attribute__((ext_vector_type(8)));
typedef bf16 bf16x4 __attribute__((ext_vector_type(4)));
typedef float f32x4 __attribute__((ext_vector_type(4)));

#define XSZ 4194304   // 4096*1024 elements (B*S x D)
#define WSZ 1048576   // 1024*1024
#define KDIM 1024

// ---------- helpers ----------
__device__ __forceinline__ void async16(const bf16* g, bf16* l) {
  __builtin_amdgcn_global_load_lds(
      (const __attribute__((address_space(1))) unsigned int*)g,
      (__attribute__((address_space(3))) unsigned int*)l, 16, 0, 0);
}

__device__ __forceinline__ bf16x8 ld8(const bf16* p) {  // two aligned b64 LDS reads
  bf16x4 lo = *(const bf16x4*)p;
  bf16x4 hi = *(const bf16x4*)(p + 4);
  return __builtin_shufflevector(lo, hi, 0, 1, 2, 3, 4, 5, 6, 7);
}

__device__ __forceinline__ void st8s(bf16* p, bf16x8 v) {  // two aligned b64 LDS writes
  *(bf16x4*)p       = __builtin_shufflevector(v, v, 0, 1, 2, 3);
  *(bf16x4*)(p + 4) = __builtin_shufflevector(v, v, 4, 5, 6, 7);
}

__device__ __forceinline__ f32x4 mfma16(bf16x8 a, bf16x8 b, f32x4 c) {
  return __builtin_amdgcn_mfma_f32_16x16x32_bf16(a, b, c, 0, 0, 0);
}

// ---------- fp32 -> bf16 cast (optionally scaled; 1/8 folded into W_q) ----------
__global__ __launch_bounds__(256) void cast_bf16(const float* __restrict__ src,
                                                 bf16* __restrict__ dst, int n, float scale) {
  int i = (blockIdx.x * 256 + threadIdx.x) * 8;
  if (i >= n) return;
  float4 a = *(const float4*)(src + i);
  float4 b = *(const float4*)(src + i + 4);
  bf16x8 o;
  o[0] = (bf16)(a.x * scale); o[1] = (bf16)(a.y * scale);
  o[2] = (bf16)(a.z * scale); o[3] = (bf16)(a.w * scale);
  o[4] = (bf16)(b.x * scale); o[5] = (bf16)(b.y * scale);
  o[6] = (bf16)(b.z * scale); o[7] = (bf16)(b.w * scale);
  *(bf16x8*)(dst + i) = o;
}

// ---------- m97-style NT GEMM core: C[128x128] += A[m,:] . B[n,:] ----------
// A: MxK row-major, Bm: NxK row-major (i.e. X @ W^T), K = 1024.
__device__ __forceinline__ void gemm_nt_core(const bf16* __restrict__ A, const bf16* __restrict__ Bm,
                                             int m0, int n0, bf16* lds, f32x4 acc[4][4]) {
  const int t = threadIdx.x;
  const int lane = t & 63, wave = t >> 6;
  const int wm = wave & 1, wn = wave >> 1;
  const int quad = lane >> 4, m16 = lane & 15;
  bf16* As = lds;              // [128][32] row-major, no pad (global_load_lds constraint)
  bf16* Bs = lds + 128 * 32;
  const int c0 = t, c1 = t + 256;
  const bf16* ga0 = A + (size_t)(m0 + (c0 >> 2)) * KDIM + (c0 & 3) * 8;
  const bf16* ga1 = A + (size_t)(m0 + (c1 >> 2)) * KDIM + (c1 & 3) * 8;
  const bf16* gb0 = Bm + (size_t)(n0 + (c0 >> 2)) * KDIM + (c0 & 3) * 8;
  const bf16* gb1 = Bm + (size_t)(n0 + (c1 >> 2)) * KDIM + (c1 & 3) * 8;
  for (int kt = 0; kt < KDIM; kt += 32) {
    async16(ga0 + kt, As + c0 * 8);
    async16(ga1 + kt, As + c1 * 8);
    async16(gb0 + kt, Bs + c0 * 8);
    async16(gb1 + kt, Bs + c1 * 8);
    __syncthreads();   // drains vmcnt (global_load_lds) per __syncthreads semantics
    bf16x8 af[4], bfv[4];
    #pragma unroll
    for (int i = 0; i < 4; i++)
      af[i] = *(const bf16x8*)(As + (wm * 64 + i * 16 + m16) * 32 + quad * 8);
    #pragma unroll
    for (int i = 0; i < 4; i++)
      bfv[i] = *(const bf16x8*)(Bs + (wn * 64 + i * 16 + m16) * 32 + quad * 8);
    #pragma unroll
    for (int mi = 0; mi < 4; mi++)
      #pragma unroll
      for (int ni = 0; ni < 4; ni++)
        acc[mi][ni] = mfma16(af[mi], bfv[ni], acc[mi][ni]);
    __syncthreads();
  }
}

// ---------- fused Q/K/V projection: z selects which of the three GEMMs ----------
__global__ __launch_bounds__(256) void proj_gemm(const bf16* __restrict__ xq, const bf16* __restrict__ xk,
                                                 const bf16* __restrict__ xv, const bf16* __restrict__ wq,
                                                 const bf16* __restrict__ wk, const bf16* __restrict__ wv,
                                                 bf16* __restrict__ Qo, bf16* __restrict__ Ko,
                                                 bf16* __restrict__ Vo) {
  __shared__ bf16 lds[2 * 128 * 32];
  const int z = blockIdx.z;
  const bf16* A = (z == 0) ? xq : (z == 1) ? xk : xv;
  const bf16* W = (z == 0) ? wq : (z == 1) ? wk : wv;
  bf16* C = (z == 0) ? Qo : (z == 1) ? Ko : Vo;
  f32x4 acc[4][4];
  #pragma unroll
  for (int i = 0; i < 4; i++)
    #pragma unroll
    for (int j = 0; j < 4; j++) acc[i][j] = (f32x4){0.f, 0.f, 0.f, 0.f};
  gemm_nt_core(A, W, blockIdx.y * 128, blockIdx.x * 128, lds, acc);
  const int lane = threadIdx.x & 63, wave = threadIdx.x >> 6;
  const int wm = wave & 1, wn = wave >> 1, quad = lane >> 4, m16 = lane & 15;
  const int row0 = blockIdx.y * 128 + wm * 64;
  const int col0 = blockIdx.x * 128 + wn * 64;
  #pragma unroll
  for (int mi = 0; mi < 4; mi++)
    #pragma unroll
    for (int ni = 0; ni < 4; ni++)
      #pragma unroll
      for (int r = 0; r < 4; r++) {
        int row = row0 + mi * 16 + quad * 4 + r;   // C layout: row=quad*4+reg, col=lane&15
        int col = col0 + ni * 16 + m16;
        C[(size_t)row * 1024 + col] = (bf16)acc[mi][ni][r];
      }
}

// ---------- output projection: fp32 out + bias ----------
__global__ __launch_bounds__(256) void out_gemm(const bf16* __restrict__ Hm, const bf16* __restrict__ wo,
                                                const float* __restrict__ bias, float* __restrict__ out) {
  __shared__ bf16 lds[2 * 128 * 32];
  f32x4 acc[4][4];
  #pragma unroll
  for (int i = 0; i < 4; i++)
    #pragma unroll
    for (int j = 0; j < 4; j++) acc[i][j] = (f32x4){0.f, 0.f, 0.f, 0.f};
  gemm_nt_core(Hm, wo, blockIdx.y * 128, blockIdx.x * 128, lds, acc);
  const int lane = threadIdx.x & 63, wave = threadIdx.x >> 6;
  const int wm = wave & 1, wn = wave >> 1, quad = lane >> 4, m16 = lane & 15;
  const int row0 = blockIdx.y * 128 + wm * 64;
  const int col0 = blockIdx.x * 128 + wn * 64;
  float bv[4];
  #pragma unroll
  for (int ni = 0; ni < 4; ni++) bv[ni] = bias[col0 + ni * 16 + m16];
  #pragma unroll
  for (int mi = 0; mi < 4; mi++)
    #pragma unroll
    for (int ni = 0; ni < 4; ni++)
      #pragma unroll
      for (int r = 0; r < 4; r++) {
        int row = row0 + mi * 16 + quad * 4 + r;
        int col = col0 + ni * 16 + m16;
        out[(size_t)row * 1024 + col] = acc[mi][ni][r] + bv[ni];
      }
}

// ---------- V transpose per head-chunk: V[2048][64] -> Vt[64][2048] ----------
__global__ __launch_bounds__(256) void transpose_v(const bf16* __restrict__ V, bf16* __restrict__ Vt) {
  __shared__ bf16 T[64 * 65];  // +1 pad: conflict-free both phases
  const int t = threadIdx.x;
  const bf16* src = V + (size_t)blockIdx.y * (2048 * 64) + (size_t)blockIdx.x * 64 * 64;
  bf16* dst = Vt + (size_t)blockIdx.y * (2048 * 64) + (size_t)blockIdx.x * 64;
  #pragma unroll
  for (int j = 0; j < 2; j++) {
    int c = t + j * 256;
    int row = c >> 3, col8 = (c & 7) * 8;
    bf16x8 v = *(const bf16x8*)(src + row * 64 + col8);
    #pragma unroll
    for (int i = 0; i < 8; i++) T[row * 65 + col8 + i] = v[i];
  }
  __syncthreads();
  #pragma unroll
  for (int j = 0; j < 2; j++) {
    int c = t + j * 256;
    int d = c >> 3, k8 = (c & 7) * 8;
    bf16x8 o;
    #pragma unroll
    for (int i = 0; i < 8; i++) o[i] = T[(k8 + i) * 65 + d];
    *(bf16x8*)(dst + (size_t)d * 2048 + k8) = o;
  }
}

// ---------- flash attention per (b,h): Q,K (2048x64), Vt (64x2048) -> O (2048x64) ----------
// Q pre-scaled by 1/8 (folded into W_q cast). 1x4 wave layout: wave owns 32 q-rows x all cols
// -> softmax reductions are shuffle-only within 16-lane groups. Ks and Ps alias one LDS region
// (3rd barrier separates QK-reads from P-writes) to stay under 64 KB.
#define KS_STRIDE 68    // 136 B rows: ~4-way read conflicts, b64-aligned
#define PS_STRIDE 132   // 264 B rows
#define VS_STRIDE 132
#define KP_ELEMS (128 * PS_STRIDE)   // 16896 elems, also covers Ks (128*68=8704)

__global__ __launch_bounds__(256, 2) void attn_kernel(const bf16* __restrict__ Qg,
                                                      const bf16* __restrict__ Kg,
                                                      const bf16* __restrict__ Vtg,
                                                      bf16* __restrict__ Og) {
  __shared__ bf16 smem[KP_ELEMS + 64 * VS_STRIDE];  // 50688 B
  bf16* KsPs = smem;
  bf16* Vs = smem + KP_ELEMS;
  const int t = threadIdx.x;
  const int lane = t & 63, wave = t >> 6;
  const int quad = lane >> 4, m16 = lane & 15;
  const size_t base = (size_t)blockIdx.y * (2048 * 64);
  const bf16* Qp = Qg + base + (size_t)blockIdx.x * 128 * 64;
  const bf16* Kp = Kg + base;
  const bf16* Vp = Vtg + base;

  // Q fragments live in registers for the whole K loop (A layout: m=lane&15, k=quad*8+j)
  bf16x8 qf[2][2];
  #pragma unroll
  for (int mi = 0; mi < 2; mi++)
    #pragma unroll
    for (int kc = 0; kc < 2; kc++)
      qf[mi][kc] = *(const bf16x8*)(Qp + (size_t)(wave * 32 + mi * 16 + m16) * 64 + kc * 32 + quad * 8);

  f32x4 oacc[2][4];
  #pragma unroll
  for (int mi = 0; mi < 2; mi++)
    #pragma unroll
    for (int nd = 0; nd < 4; nd++) oacc[mi][nd] = (f32x4){0.f, 0.f, 0.f, 0.f};
  float mrow[2][4], lrow[2][4];
  #pragma unroll
  for (int mi = 0; mi < 2; mi++)
    #pragma unroll
    for (int r = 0; r < 4; r++) { mrow[mi][r] = -INFINITY; lrow[mi][r] = 0.f; }

  for (int kt = 0; kt < 2048; kt += 128) {
    // stage K tile (128x64) into KsPs @ stride 68
    #pragma unroll
    for (int j = 0; j < 4; j++) {
      int c = t + j * 256;
      int row = c >> 3, col8 = (c & 7) * 8;
      bf16x8 v = *(const bf16x8*)(Kp + (size_t)(kt + row) * 64 + col8);
      st8s(KsPs + row * KS_STRIDE + col8, v);
    }
    // stage V^T tile (64 x 128) into Vs @ stride 132
    #pragma unroll
    for (int j = 0; j < 4; j++) {
      int c = t + j * 256;
      int d = c >> 4, col8 = (c & 15) * 8;
      bf16x8 v = *(const bf16x8*)(Vp + (size_t)d * 2048 + kt + col8);
      st8s(Vs + d * VS_STRIDE + col8, v);
    }
    __syncthreads();

    // S = (Q/8) . K^T   (wave w: rows w*32..w*32+31, cols 0..127)
    f32x4 sacc[2][8];
    #pragma unroll
    for (int mi = 0; mi < 2; mi++)
      #pragma unroll
      for (int ni = 0; ni < 8; ni++) sacc[mi][ni] = (f32x4){0.f, 0.f, 0.f, 0.f};
    #pragma unroll
    for (int kc = 0; kc < 2; kc++) {
      bf16x8 kf[8];
      #pragma unroll
      for (int ni = 0; ni < 8; ni++)
        kf[ni] = ld8(KsPs + (ni * 16 + m16) * KS_STRIDE + kc * 32 + quad * 8);
      #pragma unroll
      for (int mi = 0; mi < 2; mi++)
        #pragma unroll
        for (int ni = 0; ni < 8; ni++)
          sacc[mi][ni] = mfma16(qf[mi][kc], kf[ni], sacc[mi][ni]);
    }
    __syncthreads();   // all waves done reading Ks before P overwrites the region

    // online softmax; write P (bf16) to Ps rows [wave*32, +32) (wave-private)
    #pragma unroll
    for (int mi = 0; mi < 2; mi++) {
      #pragma unroll
      for (int r = 0; r < 4; r++) {
        float mx = sacc[mi][0][r];
        #pragma unroll
        for (int ni = 1; ni < 8; ni++) mx = fmaxf(mx, sacc[mi][ni][r]);
        #pragma unroll
        for (int s = 1; s < 16; s <<= 1) mx = fmaxf(mx, __shfl_xor(mx, s, 64));
        float mold = mrow[mi][r];
        float mnew = fmaxf(mold, mx);
        float a = __expf(mold - mnew);   // first tile: exp(-inf) = 0
        int qrow = wave * 32 + mi * 16 + quad * 4 + r;
        float sum = 0.f;
        #pragma unroll
        for (int ni = 0; ni < 8; ni++) {
          float p = __expf(sacc[mi][ni][r] - mnew);
          sum += p;
          KsPs[qrow * PS_STRIDE + ni * 16 + m16] = (bf16)p;
        }
        #pragma unroll
        for (int s = 1; s < 16; s <<= 1) sum += __shfl_xor(sum, s, 64);
        lrow[mi][r] = lrow[mi][r] * a + sum;
        mrow[mi][r] = mnew;
        #pragma unroll
        for (int nd = 0; nd < 4; nd++) oacc[mi][nd][r] *= a;
      }
    }

    // O += P . V  (A-frags from own Ps rows -> no barrier needed; B-frags from Vs)
    #pragma unroll
    for (int kc = 0; kc < 4; kc++) {
      bf16x8 pf[2], vf[4];
      #pragma unroll
      for (int mi = 0; mi < 2; mi++)
        pf[mi] = ld8(KsPs + (wave * 32 + mi * 16 + m16) * PS_STRIDE + kc * 32 + quad * 8);
      #pragma unroll
      for (int nd = 0; nd < 4; nd++)
        vf[nd] = ld8(Vs + (nd * 16 + m16) * VS_STRIDE + kc * 32 + quad * 8);
      #pragma unroll
      for (int mi = 0; mi < 2; mi++)
        #pragma unroll
        for (int nd = 0; nd < 4; nd++)
          oacc[mi][nd] = mfma16(pf[mi], vf[nd], oacc[mi][nd]);
    }
    __syncthreads();   // done reading Ps/Vs before next tile load
  }

  // epilogue: O /= l, store bf16 into H (same raw-view layout as Q/K/V)
  #pragma unroll
  for (int mi = 0; mi < 2; mi++)
    #pragma unroll
    for (int r = 0; r < 4; r++) {
      float inv = 1.f / lrow[mi][r];
      int q = blockIdx.x * 128 + wave * 32 + mi * 16 + quad * 4 + r;
      #pragma unroll
      for (int nd = 0; nd < 4; nd++)
        Og[base + (size_t)q * 64 + nd * 16 + m16] = (bf16)(oacc[mi][nd][r] * inv);
    }
}

// ---------- launch ----------
extern "C" void kernel_launch(void* const* d_in, const int* in_sizes, int n_in,
                              void* d_out, int out_size, void* d_ws, size_t ws_size,
                              hipStream_t stream) {
  const float* Xq = (const float*)d_in[0];
  const float* Xk = (const float*)d_in[1];
  const float* Xv = (const float*)d_in[2];
  const float* Wq = (const float*)d_in[3];
  const float* Wk = (const float*)d_in[4];
  const float* Wv = (const float*)d_in[5];
  const float* Wo = (const float*)d_in[6];
  const float* bo = (const float*)d_in[7];

  bf16* ws = (bf16*)d_ws;
  bf16* xq = ws;                 // 4096x1024 bf16
  bf16* xk = ws + XSZ;
  bf16* xv = ws + 2 * (size_t)XSZ;
  bf16* wq = ws + 3 * (size_t)XSZ;
  bf16* wk = wq + WSZ;
  bf16* wv = wk + WSZ;
  bf16* wo = wv + WSZ;
  bf16* q  = wo + WSZ;           // Q (pre-scaled by 1/8), raw-view layout
  bf16* k  = q + XSZ;
  bf16* v  = k + XSZ;
  bf16* vt = xv;                 // alias: X_v dead after projection
  bf16* h  = xq;                 // alias: X_q dead after projection
  // total ws use: 29360128 bf16 = 56 MB

  cast_bf16<<<XSZ / 2048, 256, 0, stream>>>(Xq, xq, XSZ, 1.0f);
  cast_bf16<<<XSZ / 2048, 256, 0, stream>>>(Xk, xk, XSZ, 1.0f);
  cast_bf16<<<XSZ / 2048, 256, 0, stream>>>(Xv, xv, XSZ, 1.0f);
  cast_bf16<<<WSZ / 2048, 256, 0, stream>>>(Wq, wq, WSZ, 0.125f);  // fold 1/sqrt(dk)
  cast_bf16<<<WSZ / 2048, 256, 0, stream>>>(Wk, wk, WSZ, 1.0f);
  cast_bf16<<<WSZ / 2048, 256, 0, stream>>>(Wv, wv, WSZ, 1.0f);
  cast_bf16<<<WSZ / 2048, 256, 0, stream>>>(Wo, wo, WSZ, 1.0f);

  proj_gemm<<<dim3(8, 32, 3), 256, 0, stream>>>(xq, xk, xv, wq, wk, wv, q, k, v);
  transpose_v<<<dim3(32, 32), 256, 0, stream>>>(v, vt);
  attn_kernel<<<dim3(16, 32), 256, 0, stream>>>(q, k, vt, h);
  out_gemm<<<dim3(8, 32), 256, 0, stream>>>(h, wo, bo, (float*)d_out);
}